// Round 13
// baseline (218.199 us; speedup 1.0000x reference)
//
#include <hip/hip_runtime.h>
#include <math.h>

// EnhancedTripletLoss, B=8192, D=256, 8 classes.
// R13: R11's proven triangular MFMA mine (unchanged) + parallel k_finish
// (wave-per-anchor, 2048 blocks — removes the 64-iteration serial gather
// chain that cost ~20-30us). Selection via packed u32 keys (q(v)<<13)|idx,
// v = sq_j - 2*dot (monotone per anchor); atomicMax/Min publish; exact fp32
// recompute of mined triplet distances (F.pairwise_distance eps semantics).

typedef __attribute__((ext_vector_type(8))) short short8;
typedef __attribute__((ext_vector_type(4))) float floatx4;

#define B_N 8192
#define D_K 256

__device__ __forceinline__ unsigned short f2bf_rne(float f) {
  unsigned u = __float_as_uint(f);
  u += 0x7FFFu + ((u >> 16) & 1u);
  return (unsigned short)(u >> 16);
}

// ---- split to bf16 fragment-major + quantized row norms + init keys ----
// Tile (16 rows x 32 k) = 512 ushorts at [tile_row][tk][lane*8+j]:
// lane = quad*16 + m, row = 16*tile_row + m, k = 32*tk + quad*8 + j.
__global__ void k_split(const float* __restrict__ x, unsigned short* __restrict__ xhf,
                        float* __restrict__ sqq,
                        unsigned* __restrict__ pk, unsigned* __restrict__ nk,
                        float* __restrict__ sum, int* __restrict__ cnt,
                        int* __restrict__ done) {
  __shared__ float sw[64];
  const int tid  = threadIdx.x;
  const int lane = tid & 63;
  const int w    = tid >> 6;
  const int b    = blockIdx.x;        // tile_row
  const int m    = lane & 15;
  const int quad = lane >> 4;
  const int row  = b * 16 + m;

  float s = 0.f;
#pragma unroll
  for (int h = 0; h < 2; ++h) {
    int tk = w + h * 4;
    int kk = tk * 32 + quad * 8;
    float4 f0 = *reinterpret_cast<const float4*>(x + (size_t)row * D_K + kk);
    float4 f1 = *reinterpret_cast<const float4*>(x + (size_t)row * D_K + kk + 4);
    s += f0.x * f0.x + f0.y * f0.y + f0.z * f0.z + f0.w * f0.w;
    s += f1.x * f1.x + f1.y * f1.y + f1.z * f1.z + f1.w * f1.w;
    ushort4 lo, hi;
    lo.x = f2bf_rne(f0.x); lo.y = f2bf_rne(f0.y); lo.z = f2bf_rne(f0.z); lo.w = f2bf_rne(f0.w);
    hi.x = f2bf_rne(f1.x); hi.y = f2bf_rne(f1.y); hi.z = f2bf_rne(f1.z); hi.w = f2bf_rne(f1.w);
    size_t o = ((size_t)b * 8 + tk) * 512 + lane * 8;
    *reinterpret_cast<ushort4*>(xhf + o)     = lo;
    *reinterpret_cast<ushort4*>(xhf + o + 4) = hi;
  }
  s += __shfl_xor(s, 16);
  s += __shfl_xor(s, 32);
  if (quad == 0) sw[w * 16 + m] = s;
  __syncthreads();
  if (tid < 16) {
    int i = b * 16 + tid;
    float t = sw[tid] + sw[16 + tid] + sw[32 + tid] + sw[48 + tid];
    sqq[i] = fmaf(t, 128.f, 262144.f);   // pre-quantized for key calc
    pk[i] = 0u;                          // selection-key init
    nk[i] = 0xFFFFFFFFu;
  }
  if (b == 0 && tid == 0) { *sum = 0.f; *cnt = 0; *done = 0; }
}

// ---- MFMA Gram + two-sided hard mining over the upper triangle ----
__global__ __launch_bounds__(256) void k_mine13(
    const unsigned short* __restrict__ xhf, const int* __restrict__ lab,
    const float* __restrict__ sqq,
    unsigned* __restrict__ pk, unsigned* __restrict__ nk) {
  __shared__ unsigned short Alds[8 * 8 * 512];   // 64 KB: [mtile 8][tk 8][512]

  // decode linear block id -> (bi, bj), bi <= bj, over 64x64 block grid
  int t  = blockIdx.x;
  int bi = (int)(64.5f - sqrtf(64.5f * 64.5f - 2.f * (float)t));
  int b0 = 64 * bi - (bi * (bi - 1)) / 2;
  if (t < b0) { bi--; b0 = 64 * bi - (bi * (bi - 1)) / 2; }
  else {
    int b1 = 64 * (bi + 1) - ((bi + 1) * bi) / 2;
    if (t >= b1) { bi++; b0 = b1; }
  }
  const int bj = bi + (t - b0);

  const int tid  = threadIdx.x;
  const int lane = tid & 63;
  const int w    = tid >> 6;
  const int wi   = w >> 1, wj = w & 1;
  const int quad = lane >> 4, l15 = lane & 15;
  const int i0   = bi * 128;

  // stage A: one contiguous 64 KB copy (already fragment-major)
  {
    const short8* src = reinterpret_cast<const short8*>(xhf + (size_t)bi * 32768);
    short8* dst = reinterpret_cast<short8*>(Alds);
#pragma unroll
    for (int it = 0; it < 16; ++it) dst[it * 256 + tid] = src[it * 256 + tid];
  }

  // per-anchor-row state: r = mt*4+reg -> ir = i0 + wi*64 + mt*16 + quad*4 + reg
  unsigned pkey[16], nkey[16];
  unsigned lip0 = 0, lip1 = 0;
  float    sqi[16];
#pragma unroll
  for (int r = 0; r < 16; ++r) {
    pkey[r] = 0u; nkey[r] = 0xFFFFFFFFu;
    int ir = i0 + wi * 64 + (r >> 2) * 16 + quad * 4 + (r & 3);
    unsigned lv = (unsigned)lab[ir] & 0xFu;
    if (r < 8) lip0 |= lv << (r * 4); else lip1 |= lv << ((r - 8) * 4);
    sqi[r] = sqq[ir];
  }
  __syncthreads();   // the only barrier

  const unsigned short* Bw = xhf + ((size_t)(bj * 8 + wj * 4) * 8) * 512 + lane * 8;
  const unsigned short* Aw = Alds + (size_t)wi * 32 * 512 + lane * 8;

  floatx4 acc[16];
#pragma unroll
  for (int q = 0; q < 16; ++q) acc[q] = (floatx4)0.f;

#pragma unroll
  for (int tk = 0; tk < 8; ++tk) {
    short8 Bf[4];
#pragma unroll
    for (int nt = 0; nt < 4; ++nt)
      Bf[nt] = *reinterpret_cast<const short8*>(Bw + nt * 4096 + tk * 512);
    short8 Af[4];
#pragma unroll
    for (int mt = 0; mt < 4; ++mt)
      Af[mt] = *reinterpret_cast<const short8*>(Aw + (size_t)(mt * 8 + tk) * 512);
#pragma unroll
    for (int mt = 0; mt < 4; ++mt)
#pragma unroll
      for (int nt = 0; nt < 4; ++nt)
        acc[mt * 4 + nt] = __builtin_amdgcn_mfma_f32_16x16x32_bf16(
            Af[mt], Bf[nt], acc[mt * 4 + nt], 0, 0, 0);
  }

  // two-sided selection epilogue.
  // i-side: v_ij = sq_j - 2*dot -> key (cvt(sjq-256*dot)<<13)|j, umax/umin.
  // j-side: v_ji = sq_i - 2*dot -> key (cvt(sqi-256*dot)<<13)|i, same eq.
  // Diagonal blocks double-update: idempotent for max/min. Self-pair never
  // wins argmax-pos (its v = -sq is the per-row minimum).
#pragma unroll
  for (int nt = 0; nt < 4; ++nt) {
    int      j  = bj * 128 + wj * 64 + nt * 16 + l15;
    unsigned jl = (unsigned)lab[j] & 0xFu;
    float    sj = sqq[j];
    unsigned jp = 0u, jn = 0xFFFFFFFFu;
#pragma unroll
    for (int r = 0; r < 16; ++r) {
      int mt = r >> 2, reg = r & 3;
      float dot = acc[mt * 4 + nt][reg];
      int   ir  = i0 + wi * 64 + mt * 16 + quad * 4 + reg;
      unsigned lr = (r < 8 ? (lip0 >> (r * 4)) : (lip1 >> ((r - 8) * 4))) & 0xFu;
      bool eq = (jl == lr);
      // i-side
      unsigned kqi  = (unsigned)fmaf(-256.f, dot, sj);
      unsigned keyi = (kqi << 13) | (unsigned)j;
      unsigned pci = eq ? keyi : 0u;
      unsigned nci = eq ? 0xFFFFFFFFu : keyi;
      pkey[r] = pkey[r] > pci ? pkey[r] : pci;
      nkey[r] = nkey[r] < nci ? nkey[r] : nci;
      // j-side
      unsigned kqj  = (unsigned)fmaf(-256.f, dot, sqi[r]);
      unsigned keyj = (kqj << 13) | (unsigned)ir;
      unsigned pcj = eq ? keyj : 0u;
      unsigned ncj = eq ? 0xFFFFFFFFu : keyj;
      jp = jp > pcj ? jp : pcj;
      jn = jn < ncj ? jn : ncj;
    }
    // reduce j-side across the 4 quads sharing this j (lane^16, lane^32)
#pragma unroll
    for (int m = 16; m < 64; m <<= 1) {
      unsigned op = (unsigned)__shfl_xor((int)jp, m);
      unsigned on = (unsigned)__shfl_xor((int)jn, m);
      jp = jp > op ? jp : op;
      jn = jn < on ? jn : on;
    }
    if (quad == 0) {
      if (jp != 0u)          atomicMax(&pk[j], jp);
      if (jn != 0xFFFFFFFFu) atomicMin(&nk[j], jn);
    }
  }

  // reduce i-side across the 16 l15-lanes of each quad
#pragma unroll
  for (int r = 0; r < 16; ++r) {
    unsigned p = pkey[r], n = nkey[r];
#pragma unroll
    for (int m = 1; m < 16; m <<= 1) {
      unsigned op = (unsigned)__shfl_xor((int)p, m);
      unsigned on = (unsigned)__shfl_xor((int)n, m);
      p = p > op ? p : op;
      n = n < on ? n : on;
    }
    if (l15 == 0) {
      int ir = i0 + wi * 64 + (r >> 2) * 16 + quad * 4 + (r & 3);
      if (p != 0u)          atomicMax(&pk[ir], p);
      if (n != 0xFFFFFFFFu) atomicMin(&nk[ir], n);
    }
  }
}

// ---- exact fp32 triplet distances + loss; wave-per-anchor (no serial loop) ----
__global__ void k_finish(const float* __restrict__ x,
                         const unsigned* __restrict__ pk, const unsigned* __restrict__ nk,
                         float* __restrict__ sum, int* __restrict__ cnt,
                         int* __restrict__ done, float* __restrict__ out) {
  __shared__ float ssum[4];
  __shared__ int   scnt[4];
  const int w = threadIdx.x >> 6, lane = threadIdx.x & 63;
  const int a = blockIdx.x * 4 + w;

  unsigned p = pk[a];
  unsigned n = nk[a];
  bool valid = (p != 0u) && (n != 0xFFFFFFFFu);
  int  pidx = valid ? (int)(p & 8191u) : 0;
  int  nidx = valid ? (int)(n & 8191u) : 0;

  float4 xa = *reinterpret_cast<const float4*>(x + (size_t)a * D_K + lane * 4);
  float4 xp = *reinterpret_cast<const float4*>(x + (size_t)pidx * D_K + lane * 4);
  float4 xn = *reinterpret_cast<const float4*>(x + (size_t)nidx * D_K + lane * 4);
  float dx, sp = 0.f, sn = 0.f;
  dx = xa.x - xp.x + 1e-6f; sp = fmaf(dx, dx, sp);
  dx = xa.y - xp.y + 1e-6f; sp = fmaf(dx, dx, sp);
  dx = xa.z - xp.z + 1e-6f; sp = fmaf(dx, dx, sp);
  dx = xa.w - xp.w + 1e-6f; sp = fmaf(dx, dx, sp);
  dx = xa.x - xn.x + 1e-6f; sn = fmaf(dx, dx, sn);
  dx = xa.y - xn.y + 1e-6f; sn = fmaf(dx, dx, sn);
  dx = xa.z - xn.z + 1e-6f; sn = fmaf(dx, dx, sn);
  dx = xa.w - xn.w + 1e-6f; sn = fmaf(dx, dx, sn);
#pragma unroll
  for (int o = 32; o > 0; o >>= 1) {
    sp += __shfl_down(sp, o, 64);
    sn += __shfl_down(sn, o, 64);
  }
  float lsum = 0.f; int lcnt = 0;
  if (lane == 0 && valid) {
    float per = sqrtf(sp) - sqrtf(sn) + 0.3f;
    if (per > 0.f) lsum = per;
    lcnt = 1;
  }
  if (lane == 0) { ssum[w] = lsum; scnt[w] = lcnt; }
  __syncthreads();
  if (threadIdx.x == 0) {
    atomicAdd(sum, ssum[0] + ssum[1] + ssum[2] + ssum[3]);
    atomicAdd(cnt, scnt[0] + scnt[1] + scnt[2] + scnt[3]);
    __threadfence();
    int prev = atomicAdd(done, 1);
    if (prev == gridDim.x - 1) {
      float s = atomicAdd(sum, 0.f);
      int   cc = atomicAdd(cnt, 0);
      if (cc < 1) cc = 1;
      out[0] = s / (float)cc;
    }
  }
}

extern "C" void kernel_launch(void* const* d_in, const int* in_sizes, int n_in,
                              void* d_out, int out_size, void* d_ws, size_t ws_size,
                              hipStream_t stream) {
  const float* x   = (const float*)d_in[0];
  const int*   lab = (const int*)d_in[1];
  float*       out = (float*)d_out;

  char* ws = (char*)d_ws;
  unsigned short* xhf = (unsigned short*)ws;                      // 4 MB
  float* sqq = (float*)(ws + (size_t)4608 * 1024);                // 32 KB
  char*  pb = ws + (size_t)4608 * 1024 + 65536;
  unsigned* pk  = (unsigned*)(pb);                                // 32 KB
  unsigned* nk  = (unsigned*)(pb + 32768);                        // 32 KB
  float* sum  = (float*)(pb + 65536);
  int*   cnt  = (int*)(sum + 1);
  int*   done = (int*)(sum + 2);

  k_split<<<B_N / 16, 256, 0, stream>>>(x, xhf, sqq, pk, nk, sum, cnt, done);
  k_mine13<<<2080, 256, 0, stream>>>(xhf, lab, sqq, pk, nk);
  k_finish<<<B_N / 4, 256, 0, stream>>>(x, pk, nk, sum, cnt, done, out);
}

// Round 14
// 205.617 us; speedup vs baseline: 1.0612x; 1.0612x over previous
//
#include <hip/hip_runtime.h>
#include <math.h>

// EnhancedTripletLoss, B=8192, D=256, 8 classes.
// R14: triangular two-sided mining with 64x64 block-pair tiles (8256 blocks):
// A-panel 32 KB LDS -> 4 blocks/CU x 4 waves = 16 waves/CU (2x R11's hiding).
// Wave tile 32x32 (acc = 4 floatx4 AGPRs). Same total MFMA / VALU / pair work
// as R11, double the latency overlap. k_finish reverted to R11's proven
// 128-block form (384 same-line atomics, not 6144 — R13's 84us regression).
// Selection keys (q(v)<<13)|idx, v = sq_j - 2*dot (monotone); atomicMax/Min
// publish; exact fp32 recompute of mined distances (pairwise_distance eps).

typedef __attribute__((ext_vector_type(8))) short short8;
typedef __attribute__((ext_vector_type(4))) float floatx4;

#define B_N 8192
#define D_K 256

__device__ __forceinline__ unsigned short f2bf_rne(float f) {
  unsigned u = __float_as_uint(f);
  u += 0x7FFFu + ((u >> 16) & 1u);
  return (unsigned short)(u >> 16);
}

// ---- split to bf16 fragment-major + quantized row norms + init keys ----
// Tile (16 rows x 32 k) = 512 ushorts at [tile_row][tk][lane*8+j]:
// lane = quad*16 + m, row = 16*tile_row + m, k = 32*tk + quad*8 + j.
__global__ void k_split(const float* __restrict__ x, unsigned short* __restrict__ xhf,
                        float* __restrict__ sqq,
                        unsigned* __restrict__ pk, unsigned* __restrict__ nk,
                        float* __restrict__ sum, int* __restrict__ cnt,
                        int* __restrict__ done) {
  __shared__ float sw[64];
  const int tid  = threadIdx.x;
  const int lane = tid & 63;
  const int w    = tid >> 6;
  const int b    = blockIdx.x;        // tile_row
  const int m    = lane & 15;
  const int quad = lane >> 4;
  const int row  = b * 16 + m;

  float s = 0.f;
#pragma unroll
  for (int h = 0; h < 2; ++h) {
    int tk = w + h * 4;
    int kk = tk * 32 + quad * 8;
    float4 f0 = *reinterpret_cast<const float4*>(x + (size_t)row * D_K + kk);
    float4 f1 = *reinterpret_cast<const float4*>(x + (size_t)row * D_K + kk + 4);
    s += f0.x * f0.x + f0.y * f0.y + f0.z * f0.z + f0.w * f0.w;
    s += f1.x * f1.x + f1.y * f1.y + f1.z * f1.z + f1.w * f1.w;
    ushort4 lo, hi;
    lo.x = f2bf_rne(f0.x); lo.y = f2bf_rne(f0.y); lo.z = f2bf_rne(f0.z); lo.w = f2bf_rne(f0.w);
    hi.x = f2bf_rne(f1.x); hi.y = f2bf_rne(f1.y); hi.z = f2bf_rne(f1.z); hi.w = f2bf_rne(f1.w);
    size_t o = ((size_t)b * 8 + tk) * 512 + lane * 8;
    *reinterpret_cast<ushort4*>(xhf + o)     = lo;
    *reinterpret_cast<ushort4*>(xhf + o + 4) = hi;
  }
  s += __shfl_xor(s, 16);
  s += __shfl_xor(s, 32);
  if (quad == 0) sw[w * 16 + m] = s;
  __syncthreads();
  if (tid < 16) {
    int i = b * 16 + tid;
    float t = sw[tid] + sw[16 + tid] + sw[32 + tid] + sw[48 + tid];
    sqq[i] = fmaf(t, 128.f, 262144.f);   // pre-quantized for key calc
    pk[i] = 0u;
    nk[i] = 0xFFFFFFFFu;
  }
  if (b == 0 && tid == 0) { *sum = 0.f; *cnt = 0; *done = 0; }
}

// ---- MFMA Gram + two-sided mining, 64x64 triangular tiles, 16 waves/CU ----
__global__ __launch_bounds__(256) void k_mine14(
    const unsigned short* __restrict__ xhf, const int* __restrict__ lab,
    const float* __restrict__ sqq,
    unsigned* __restrict__ pk, unsigned* __restrict__ nk) {
  __shared__ unsigned short Alds[4 * 8 * 512];   // 32 KB: [mtile 4][tk 8][512]

  // decode linear block id -> (bi, bj), bi <= bj, over 128x128 tile grid
  int t  = blockIdx.x;
  int bi = (int)(128.5f - sqrtf(16512.25f - 2.f * (float)t));
  int b0 = 128 * bi - (bi * (bi - 1)) / 2;
  if (t < b0) { bi--; b0 = 128 * bi - (bi * (bi - 1)) / 2; }
  else {
    int b1 = 128 * (bi + 1) - ((bi + 1) * bi) / 2;
    if (t >= b1) { bi++; b0 = b1; }
  }
  const int bj = bi + (t - b0);

  const int tid  = threadIdx.x;
  const int lane = tid & 63;
  const int w    = tid >> 6;
  const int wi   = w >> 1, wj = w & 1;   // 2x2 waves, wave tile 32x32
  const int quad = lane >> 4, l15 = lane & 15;
  const int i0   = bi * 64;

  // stage A panel (64 rows, fragment-major): contiguous 32 KB copy
  {
    const short8* src = reinterpret_cast<const short8*>(xhf + (size_t)bi * 16384);
    short8* dst = reinterpret_cast<short8*>(Alds);
#pragma unroll
    for (int it = 0; it < 8; ++it) dst[it * 256 + tid] = src[it * 256 + tid];
  }

  // rows of this wave: ir = i0 + wi*32 + (r>>2)*16 + quad*4 + (r&3), r in 0..7
  unsigned pkey[8], nkey[8];
  unsigned lip = 0;
  float    sqi[8];
#pragma unroll
  for (int r = 0; r < 8; ++r) {
    pkey[r] = 0u; nkey[r] = 0xFFFFFFFFu;
    int ir = i0 + wi * 32 + (r >> 2) * 16 + quad * 4 + (r & 3);
    lip |= ((unsigned)lab[ir] & 0xFu) << (r * 4);
    sqi[r] = sqq[ir];
  }
  __syncthreads();   // the only barrier

  const unsigned short* Bw = xhf + ((size_t)(bj * 4 + wj * 2) * 8) * 512 + lane * 8;
  const unsigned short* Aw = Alds + (size_t)(wi * 2) * 8 * 512 + lane * 8;

  floatx4 acc[4];
#pragma unroll
  for (int q = 0; q < 4; ++q) acc[q] = (floatx4)0.f;

#pragma unroll
  for (int tk = 0; tk < 8; ++tk) {
    short8 Bf[2];
#pragma unroll
    for (int nt = 0; nt < 2; ++nt)
      Bf[nt] = *reinterpret_cast<const short8*>(Bw + nt * 4096 + tk * 512);
    short8 Af[2];
#pragma unroll
    for (int mt = 0; mt < 2; ++mt)
      Af[mt] = *reinterpret_cast<const short8*>(Aw + (size_t)(mt * 8 + tk) * 512);
#pragma unroll
    for (int mt = 0; mt < 2; ++mt)
#pragma unroll
      for (int nt = 0; nt < 2; ++nt)
        acc[mt * 2 + nt] = __builtin_amdgcn_mfma_f32_16x16x32_bf16(
            Af[mt], Bf[nt], acc[mt * 2 + nt], 0, 0, 0);
  }

  // two-sided selection epilogue.
  // i-side: v_ij = sq_j - 2*dot -> key (cvt(sjq-256*dot)<<13)|j, umax/umin.
  // j-side: v_ji = sq_i - 2*dot -> key (cvt(sqi-256*dot)<<13)|i, same eq.
  // Diagonal blocks double-update (idempotent); self never wins argmax-pos.
#pragma unroll
  for (int nt = 0; nt < 2; ++nt) {
    int      j  = bj * 64 + wj * 32 + nt * 16 + l15;
    unsigned jl = (unsigned)lab[j] & 0xFu;
    float    sj = sqq[j];
    unsigned jp = 0u, jn = 0xFFFFFFFFu;
#pragma unroll
    for (int r = 0; r < 8; ++r) {
      float dot = acc[(r >> 2) * 2 + nt][r & 3];
      int   ir  = i0 + wi * 32 + (r >> 2) * 16 + quad * 4 + (r & 3);
      bool  eq  = (jl == ((lip >> (r * 4)) & 0xFu));
      // i-side
      unsigned kqi  = (unsigned)fmaf(-256.f, dot, sj);
      unsigned keyi = (kqi << 13) | (unsigned)j;
      unsigned pci = eq ? keyi : 0u;
      unsigned nci = eq ? 0xFFFFFFFFu : keyi;
      pkey[r] = pkey[r] > pci ? pkey[r] : pci;
      nkey[r] = nkey[r] < nci ? nkey[r] : nci;
      // j-side
      unsigned kqj  = (unsigned)fmaf(-256.f, dot, sqi[r]);
      unsigned keyj = (kqj << 13) | (unsigned)ir;
      unsigned pcj = eq ? keyj : 0u;
      unsigned ncj = eq ? 0xFFFFFFFFu : keyj;
      jp = jp > pcj ? jp : pcj;
      jn = jn < ncj ? jn : ncj;
    }
    // reduce j-side across the 4 quads sharing this j
#pragma unroll
    for (int m = 16; m < 64; m <<= 1) {
      unsigned op = (unsigned)__shfl_xor((int)jp, m);
      unsigned on = (unsigned)__shfl_xor((int)jn, m);
      jp = jp > op ? jp : op;
      jn = jn < on ? jn : on;
    }
    if (quad == 0) {
      if (jp != 0u)          atomicMax(&pk[j], jp);
      if (jn != 0xFFFFFFFFu) atomicMin(&nk[j], jn);
    }
  }

  // reduce i-side across the 16 l15-lanes of each quad
#pragma unroll
  for (int r = 0; r < 8; ++r) {
    unsigned p = pkey[r], n = nkey[r];
#pragma unroll
    for (int m = 1; m < 16; m <<= 1) {
      unsigned op = (unsigned)__shfl_xor((int)p, m);
      unsigned on = (unsigned)__shfl_xor((int)n, m);
      p = p > op ? p : op;
      n = n < on ? n : on;
    }
    if (l15 == 0) {
      int ir = i0 + wi * 32 + (r >> 2) * 16 + quad * 4 + (r & 3);
      if (p != 0u)          atomicMax(&pk[ir], p);
      if (n != 0xFFFFFFFFu) atomicMin(&nk[ir], n);
    }
  }
}

// ---- exact fp32 triplet distances + loss (R11's proven 128-block form) ----
__global__ void k_finish(const float* __restrict__ x,
                         const unsigned* __restrict__ pk, const unsigned* __restrict__ nk,
                         float* __restrict__ sum, int* __restrict__ cnt,
                         int* __restrict__ done, float* __restrict__ out) {
  __shared__ float ssum[4];
  __shared__ int   scnt[4];
  int w = threadIdx.x >> 6, lane = threadIdx.x & 63;
  float lsum = 0.f; int lcnt = 0;
#pragma unroll
  for (int it = 0; it < 16; ++it) {
    int a = (blockIdx.x * 4 + w) * 16 + it;
    unsigned p = pk[a];
    unsigned n = nk[a];
    bool valid = (p != 0u) && (n != 0xFFFFFFFFu);
    int  pidx = valid ? (int)(p & 8191u) : 0;
    int  nidx = valid ? (int)(n & 8191u) : 0;

    float4 xa = *reinterpret_cast<const float4*>(x + (size_t)a * D_K + lane * 4);
    float4 xp = *reinterpret_cast<const float4*>(x + (size_t)pidx * D_K + lane * 4);
    float4 xn = *reinterpret_cast<const float4*>(x + (size_t)nidx * D_K + lane * 4);
    float dx, sp = 0.f, sn = 0.f;
    dx = xa.x - xp.x + 1e-6f; sp = fmaf(dx, dx, sp);
    dx = xa.y - xp.y + 1e-6f; sp = fmaf(dx, dx, sp);
    dx = xa.z - xp.z + 1e-6f; sp = fmaf(dx, dx, sp);
    dx = xa.w - xp.w + 1e-6f; sp = fmaf(dx, dx, sp);
    dx = xa.x - xn.x + 1e-6f; sn = fmaf(dx, dx, sn);
    dx = xa.y - xn.y + 1e-6f; sn = fmaf(dx, dx, sn);
    dx = xa.z - xn.z + 1e-6f; sn = fmaf(dx, dx, sn);
    dx = xa.w - xn.w + 1e-6f; sn = fmaf(dx, dx, sn);
#pragma unroll
    for (int o = 32; o > 0; o >>= 1) {
      sp += __shfl_down(sp, o, 64);
      sn += __shfl_down(sn, o, 64);
    }
    if (lane == 0 && valid) {
      float per = sqrtf(sp) - sqrtf(sn) + 0.3f;
      if (per > 0.f) lsum += per;
      lcnt += 1;
    }
  }
  if (lane == 0) { ssum[w] = lsum; scnt[w] = lcnt; }
  __syncthreads();
  if (threadIdx.x == 0) {
    atomicAdd(sum, ssum[0] + ssum[1] + ssum[2] + ssum[3]);
    atomicAdd(cnt, scnt[0] + scnt[1] + scnt[2] + scnt[3]);
    __threadfence();
    int prev = atomicAdd(done, 1);
    if (prev == gridDim.x - 1) {
      float s = atomicAdd(sum, 0.f);
      int   cc = atomicAdd(cnt, 0);
      if (cc < 1) cc = 1;
      out[0] = s / (float)cc;
    }
  }
}

extern "C" void kernel_launch(void* const* d_in, const int* in_sizes, int n_in,
                              void* d_out, int out_size, void* d_ws, size_t ws_size,
                              hipStream_t stream) {
  const float* x   = (const float*)d_in[0];
  const int*   lab = (const int*)d_in[1];
  float*       out = (float*)d_out;

  char* ws = (char*)d_ws;
  unsigned short* xhf = (unsigned short*)ws;                      // 4 MB
  float* sqq = (float*)(ws + (size_t)4608 * 1024);                // 32 KB
  char*  pb = ws + (size_t)4608 * 1024 + 65536;
  unsigned* pk  = (unsigned*)(pb);                                // 32 KB
  unsigned* nk  = (unsigned*)(pb + 32768);                        // 32 KB
  float* sum  = (float*)(pb + 65536);
  int*   cnt  = (int*)(sum + 1);
  int*   done = (int*)(sum + 2);

  k_split<<<B_N / 16, 256, 0, stream>>>(x, xhf, sqq, pk, nk, sum, cnt, done);
  k_mine14<<<8256, 256, 0, stream>>>(xhf, lab, sqq, pk, nk);
  k_finish<<<128, 256, 0, stream>>>(x, pk, nk, sum, cnt, done, out);
}

// Round 15
// 126.963 us; speedup vs baseline: 1.7186x; 1.6195x over previous
//
#include <hip/hip_runtime.h>
#include <math.h>

// EnhancedTripletLoss, B=8192, D=256, 8 classes.
// R15: R11's triangular two-sided MFMA mine with ALL global atomics replaced
// by race-free slotted partial stores (R13 measured ~13.7ns per serialized
// same-line atomic hit -> R11's ~2.1M atomics over 1024 lines were costing
// tens of us). Band b's 128 partial slots are covered exactly once:
//   i-side of block (bi,bj): slot 2*bj+wj of band bi   (slots >= 2*bi)
//   j-side of block (bi,bj), bi!=bj: slot 2*bi+wi of band bj (slots < 2*bj)
// k_finish: coalesced 128-slot max/min reduce + exact fp32 triplet distances.

typedef __attribute__((ext_vector_type(8))) short short8;
typedef __attribute__((ext_vector_type(4))) float floatx4;

#define B_N 8192
#define D_K 256

__device__ __forceinline__ unsigned short f2bf_rne(float f) {
  unsigned u = __float_as_uint(f);
  u += 0x7FFFu + ((u >> 16) & 1u);
  return (unsigned short)(u >> 16);
}

// ---- split to bf16 fragment-major + quantized row norms ----
// Tile (16 rows x 32 k) = 512 ushorts at [tile_row][tk][lane*8+j]:
// lane = quad*16 + m, row = 16*tile_row + m, k = 32*tk + quad*8 + j.
__global__ void k_split(const float* __restrict__ x, unsigned short* __restrict__ xhf,
                        float* __restrict__ sqq,
                        float* __restrict__ sum, int* __restrict__ cnt,
                        int* __restrict__ done) {
  __shared__ float sw[64];
  const int tid  = threadIdx.x;
  const int lane = tid & 63;
  const int w    = tid >> 6;
  const int b    = blockIdx.x;        // tile_row
  const int m    = lane & 15;
  const int quad = lane >> 4;
  const int row  = b * 16 + m;

  float s = 0.f;
#pragma unroll
  for (int h = 0; h < 2; ++h) {
    int tk = w + h * 4;
    int kk = tk * 32 + quad * 8;
    float4 f0 = *reinterpret_cast<const float4*>(x + (size_t)row * D_K + kk);
    float4 f1 = *reinterpret_cast<const float4*>(x + (size_t)row * D_K + kk + 4);
    s += f0.x * f0.x + f0.y * f0.y + f0.z * f0.z + f0.w * f0.w;
    s += f1.x * f1.x + f1.y * f1.y + f1.z * f1.z + f1.w * f1.w;
    ushort4 lo, hi;
    lo.x = f2bf_rne(f0.x); lo.y = f2bf_rne(f0.y); lo.z = f2bf_rne(f0.z); lo.w = f2bf_rne(f0.w);
    hi.x = f2bf_rne(f1.x); hi.y = f2bf_rne(f1.y); hi.z = f2bf_rne(f1.z); hi.w = f2bf_rne(f1.w);
    size_t o = ((size_t)b * 8 + tk) * 512 + lane * 8;
    *reinterpret_cast<ushort4*>(xhf + o)     = lo;
    *reinterpret_cast<ushort4*>(xhf + o + 4) = hi;
  }
  s += __shfl_xor(s, 16);
  s += __shfl_xor(s, 32);
  if (quad == 0) sw[w * 16 + m] = s;
  __syncthreads();
  if (tid < 16) {
    int i = b * 16 + tid;
    float t = sw[tid] + sw[16 + tid] + sw[32 + tid] + sw[48 + tid];
    sqq[i] = fmaf(t, 128.f, 262144.f);   // pre-quantized for key calc
  }
  if (b == 0 && tid == 0) { *sum = 0.f; *cnt = 0; *done = 0; }
}

// ---- MFMA Gram + two-sided mining over the upper triangle; no atomics ----
__global__ __launch_bounds__(256) void k_mine15(
    const unsigned short* __restrict__ xhf, const int* __restrict__ lab,
    const float* __restrict__ sqq,
    unsigned* __restrict__ ppart, unsigned* __restrict__ npart) {
  __shared__ unsigned short Alds[8 * 8 * 512];   // 64 KB: [mtile 8][tk 8][512]

  // decode linear block id -> (bi, bj), bi <= bj, over 64x64 block grid
  int t  = blockIdx.x;
  int bi = (int)(64.5f - sqrtf(64.5f * 64.5f - 2.f * (float)t));
  int b0 = 64 * bi - (bi * (bi - 1)) / 2;
  if (t < b0) { bi--; b0 = 64 * bi - (bi * (bi - 1)) / 2; }
  else {
    int b1 = 64 * (bi + 1) - ((bi + 1) * bi) / 2;
    if (t >= b1) { bi++; b0 = b1; }
  }
  const int bj = bi + (t - b0);

  const int tid  = threadIdx.x;
  const int lane = tid & 63;
  const int w    = tid >> 6;
  const int wi   = w >> 1, wj = w & 1;
  const int quad = lane >> 4, l15 = lane & 15;
  const int i0   = bi * 128;

  // stage A: one contiguous 64 KB copy (already fragment-major)
  {
    const short8* src = reinterpret_cast<const short8*>(xhf + (size_t)bi * 32768);
    short8* dst = reinterpret_cast<short8*>(Alds);
#pragma unroll
    for (int it = 0; it < 16; ++it) dst[it * 256 + tid] = src[it * 256 + tid];
  }

  unsigned pkey[16], nkey[16];
  unsigned lip0 = 0, lip1 = 0;
  float    sqi[16];
#pragma unroll
  for (int r = 0; r < 16; ++r) {
    pkey[r] = 0u; nkey[r] = 0xFFFFFFFFu;
    int ir = i0 + wi * 64 + (r >> 2) * 16 + quad * 4 + (r & 3);
    unsigned lv = (unsigned)lab[ir] & 0xFu;
    if (r < 8) lip0 |= lv << (r * 4); else lip1 |= lv << ((r - 8) * 4);
    sqi[r] = sqq[ir];
  }
  __syncthreads();   // the only barrier

  const unsigned short* Bw = xhf + ((size_t)(bj * 8 + wj * 4) * 8) * 512 + lane * 8;
  const unsigned short* Aw = Alds + (size_t)wi * 32 * 512 + lane * 8;

  floatx4 acc[16];
#pragma unroll
  for (int q = 0; q < 16; ++q) acc[q] = (floatx4)0.f;

#pragma unroll
  for (int tk = 0; tk < 8; ++tk) {
    short8 Bf[4];
#pragma unroll
    for (int nt = 0; nt < 4; ++nt)
      Bf[nt] = *reinterpret_cast<const short8*>(Bw + nt * 4096 + tk * 512);
    short8 Af[4];
#pragma unroll
    for (int mt = 0; mt < 4; ++mt)
      Af[mt] = *reinterpret_cast<const short8*>(Aw + (size_t)(mt * 8 + tk) * 512);
#pragma unroll
    for (int mt = 0; mt < 4; ++mt)
#pragma unroll
      for (int nt = 0; nt < 4; ++nt)
        acc[mt * 4 + nt] = __builtin_amdgcn_mfma_f32_16x16x32_bf16(
            Af[mt], Bf[nt], acc[mt * 4 + nt], 0, 0, 0);
  }

  // two-sided selection epilogue (keys as in R11).
#pragma unroll
  for (int nt = 0; nt < 4; ++nt) {
    int      j  = bj * 128 + wj * 64 + nt * 16 + l15;
    unsigned jl = (unsigned)lab[j] & 0xFu;
    float    sj = sqq[j];
    unsigned jp = 0u, jn = 0xFFFFFFFFu;
#pragma unroll
    for (int r = 0; r < 16; ++r) {
      int mt = r >> 2, reg = r & 3;
      float dot = acc[mt * 4 + nt][reg];
      int   ir  = i0 + wi * 64 + mt * 16 + quad * 4 + reg;
      unsigned lr = (r < 8 ? (lip0 >> (r * 4)) : (lip1 >> ((r - 8) * 4))) & 0xFu;
      bool eq = (jl == lr);
      // i-side
      unsigned kqi  = (unsigned)fmaf(-256.f, dot, sj);
      unsigned keyi = (kqi << 13) | (unsigned)j;
      unsigned pci = eq ? keyi : 0u;
      unsigned nci = eq ? 0xFFFFFFFFu : keyi;
      pkey[r] = pkey[r] > pci ? pkey[r] : pci;
      nkey[r] = nkey[r] < nci ? nkey[r] : nci;
      // j-side
      unsigned kqj  = (unsigned)fmaf(-256.f, dot, sqi[r]);
      unsigned keyj = (kqj << 13) | (unsigned)ir;
      unsigned pcj = eq ? keyj : 0u;
      unsigned ncj = eq ? 0xFFFFFFFFu : keyj;
      jp = jp > pcj ? jp : pcj;
      jn = jn < ncj ? jn : ncj;
    }
    // reduce j-side across the 4 quads sharing this j
#pragma unroll
    for (int m = 16; m < 64; m <<= 1) {
      unsigned op = (unsigned)__shfl_xor((int)jp, m);
      unsigned on = (unsigned)__shfl_xor((int)jn, m);
      jp = jp > op ? jp : op;
      jn = jn < on ? jn : on;
    }
    // j-side publish: slot 2*bi+wi of band bj; skip diagonal (duplicate of i-side)
    if (quad == 0 && bi != bj) {
      size_t idx = (size_t)(2 * bi + wi) * B_N + j;
      ppart[idx] = jp;
      npart[idx] = jn;
    }
  }

  // i-side: reduce across the 16 l15-lanes, publish to slot 2*bj+wj of band bi
#pragma unroll
  for (int r = 0; r < 16; ++r) {
    unsigned p = pkey[r], n = nkey[r];
#pragma unroll
    for (int m = 1; m < 16; m <<= 1) {
      unsigned op = (unsigned)__shfl_xor((int)p, m);
      unsigned on = (unsigned)__shfl_xor((int)n, m);
      p = p > op ? p : op;
      n = n < on ? n : on;
    }
    if (l15 == 0) {
      int ir = i0 + wi * 64 + (r >> 2) * 16 + quad * 4 + (r & 3);
      size_t idx = (size_t)(2 * bj + wj) * B_N + ir;
      ppart[idx] = p;
      npart[idx] = n;
    }
  }
}

// ---- slot-reduce + exact fp32 triplet distances + loss ----
// 256 blocks x 32 anchors. Phase A: 8 thread-groups reduce 16 slots each
// (coalesced across anchors), LDS-combine. Phase B: wave-per-8-anchors
// distance recompute (F.pairwise_distance eps semantics).
__global__ void k_finish(const float* __restrict__ x,
                         const unsigned* __restrict__ ppart,
                         const unsigned* __restrict__ npart,
                         float* __restrict__ sum, int* __restrict__ cnt,
                         int* __restrict__ done, float* __restrict__ out) {
  __shared__ unsigned spk[32], snk[32];
  __shared__ float ssum[4];
  __shared__ int   scnt[4];
  const int tid = threadIdx.x;
  const int a0  = blockIdx.x * 32;

  if (tid < 32) { spk[tid] = 0u; snk[tid] = 0xFFFFFFFFu; }
  __syncthreads();

  {
    const int a    = a0 + (tid & 31);
    const int part = tid >> 5;           // 0..7 -> slots part*16 .. part*16+15
    unsigned p = 0u, n = 0xFFFFFFFFu;
#pragma unroll
    for (int s = 0; s < 16; ++s) {
      size_t idx = (size_t)(part * 16 + s) * B_N + a;
      unsigned pv = ppart[idx];
      unsigned nv = npart[idx];
      p = p > pv ? p : pv;
      n = n < nv ? n : nv;
    }
    atomicMax(&spk[tid & 31], p);        // LDS atomics: cheap, 8-way
    atomicMin(&snk[tid & 31], n);
  }
  __syncthreads();

  const int w = tid >> 6, lane = tid & 63;
  float lsum = 0.f; int lcnt = 0;
#pragma unroll
  for (int it = 0; it < 8; ++it) {
    int al = w * 8 + it;                 // 0..31
    int a  = a0 + al;
    unsigned p = spk[al];
    unsigned n = snk[al];
    bool valid = (p != 0u) && (n != 0xFFFFFFFFu);
    int  pidx = valid ? (int)(p & 8191u) : 0;
    int  nidx = valid ? (int)(n & 8191u) : 0;

    float4 xa = *reinterpret_cast<const float4*>(x + (size_t)a * D_K + lane * 4);
    float4 xp = *reinterpret_cast<const float4*>(x + (size_t)pidx * D_K + lane * 4);
    float4 xn = *reinterpret_cast<const float4*>(x + (size_t)nidx * D_K + lane * 4);
    float dx, sp = 0.f, sn = 0.f;
    dx = xa.x - xp.x + 1e-6f; sp = fmaf(dx, dx, sp);
    dx = xa.y - xp.y + 1e-6f; sp = fmaf(dx, dx, sp);
    dx = xa.z - xp.z + 1e-6f; sp = fmaf(dx, dx, sp);
    dx = xa.w - xp.w + 1e-6f; sp = fmaf(dx, dx, sp);
    dx = xa.x - xn.x + 1e-6f; sn = fmaf(dx, dx, sn);
    dx = xa.y - xn.y + 1e-6f; sn = fmaf(dx, dx, sn);
    dx = xa.z - xn.z + 1e-6f; sn = fmaf(dx, dx, sn);
    dx = xa.w - xn.w + 1e-6f; sn = fmaf(dx, dx, sn);
#pragma unroll
    for (int o = 32; o > 0; o >>= 1) {
      sp += __shfl_down(sp, o, 64);
      sn += __shfl_down(sn, o, 64);
    }
    if (lane == 0 && valid) {
      float per = sqrtf(sp) - sqrtf(sn) + 0.3f;
      if (per > 0.f) lsum += per;
      lcnt += 1;
    }
  }
  if (lane == 0) { ssum[w] = lsum; scnt[w] = lcnt; }
  __syncthreads();
  if (tid == 0) {
    atomicAdd(sum, ssum[0] + ssum[1] + ssum[2] + ssum[3]);
    atomicAdd(cnt, scnt[0] + scnt[1] + scnt[2] + scnt[3]);
    __threadfence();
    int prev = atomicAdd(done, 1);
    if (prev == gridDim.x - 1) {
      float s = atomicAdd(sum, 0.f);
      int   cc = atomicAdd(cnt, 0);
      if (cc < 1) cc = 1;
      out[0] = s / (float)cc;
    }
  }
}

extern "C" void kernel_launch(void* const* d_in, const int* in_sizes, int n_in,
                              void* d_out, int out_size, void* d_ws, size_t ws_size,
                              hipStream_t stream) {
  const float* x   = (const float*)d_in[0];
  const int*   lab = (const int*)d_in[1];
  float*       out = (float*)d_out;

  char* ws = (char*)d_ws;
  unsigned short* xhf = (unsigned short*)ws;                      // 4 MB
  float* sqq = (float*)(ws + (size_t)4608 * 1024);                // 32 KB
  char*  pb = ws + (size_t)4608 * 1024 + 65536;
  size_t seg = (size_t)128 * B_N * 4;                             // 4 MB each
  unsigned* ppart = (unsigned*)(pb);
  unsigned* npart = (unsigned*)(pb + seg);
  float* sum  = (float*)(pb + 2 * seg);
  int*   cnt  = (int*)(sum + 1);
  int*   done = (int*)(sum + 2);

  k_split<<<B_N / 16, 256, 0, stream>>>(x, xhf, sqq, sum, cnt, done);
  k_mine15<<<2080, 256, 0, stream>>>(xhf, lab, sqq, ppart, npart);
  k_finish<<<B_N / 32, 256, 0, stream>>>(x, ppart, npart, sum, cnt, done, out);
}

// Round 16
// 121.737 us; speedup vs baseline: 1.7924x; 1.0429x over previous
//
#include <hip/hip_runtime.h>
#include <math.h>

// EnhancedTripletLoss, B=8192, D=256, 8 classes.
// R16: R15's triangular two-sided slotted mine (no global atomics) with
// 512-thread blocks: 8 waves (4 wi x 2 wj), wave tile 32x64, sharing the same
// 64 KB A-panel -> 2 blocks/CU x 8 waves = 16 waves/CU (2x R15's hiding) and
// ~70 live arch VGPRs/thread. j-side combined across wi-wave pairs via a 4 KB
// LDS buffer so the R15 slot scheme (j-side 2bi+{0,1}, i-side 2bj+wj, no
// holes) and k_finish stay identical. Exact fp32 recompute in k_finish.

typedef __attribute__((ext_vector_type(8))) short short8;
typedef __attribute__((ext_vector_type(4))) float floatx4;

#define B_N 8192
#define D_K 256

__device__ __forceinline__ unsigned short f2bf_rne(float f) {
  unsigned u = __float_as_uint(f);
  u += 0x7FFFu + ((u >> 16) & 1u);
  return (unsigned short)(u >> 16);
}

// ---- split to bf16 fragment-major + quantized row norms ----
// Tile (16 rows x 32 k) = 512 ushorts at [tile_row][tk][lane*8+j]:
// lane = quad*16 + m, row = 16*tile_row + m, k = 32*tk + quad*8 + j.
__global__ void k_split(const float* __restrict__ x, unsigned short* __restrict__ xhf,
                        float* __restrict__ sqq,
                        float* __restrict__ sum, int* __restrict__ cnt,
                        int* __restrict__ done) {
  __shared__ float sw[64];
  const int tid  = threadIdx.x;
  const int lane = tid & 63;
  const int w    = tid >> 6;
  const int b    = blockIdx.x;        // tile_row
  const int m    = lane & 15;
  const int quad = lane >> 4;
  const int row  = b * 16 + m;

  float s = 0.f;
#pragma unroll
  for (int h = 0; h < 2; ++h) {
    int tk = w + h * 4;
    int kk = tk * 32 + quad * 8;
    float4 f0 = *reinterpret_cast<const float4*>(x + (size_t)row * D_K + kk);
    float4 f1 = *reinterpret_cast<const float4*>(x + (size_t)row * D_K + kk + 4);
    s += f0.x * f0.x + f0.y * f0.y + f0.z * f0.z + f0.w * f0.w;
    s += f1.x * f1.x + f1.y * f1.y + f1.z * f1.z + f1.w * f1.w;
    ushort4 lo, hi;
    lo.x = f2bf_rne(f0.x); lo.y = f2bf_rne(f0.y); lo.z = f2bf_rne(f0.z); lo.w = f2bf_rne(f0.w);
    hi.x = f2bf_rne(f1.x); hi.y = f2bf_rne(f1.y); hi.z = f2bf_rne(f1.z); hi.w = f2bf_rne(f1.w);
    size_t o = ((size_t)b * 8 + tk) * 512 + lane * 8;
    *reinterpret_cast<ushort4*>(xhf + o)     = lo;
    *reinterpret_cast<ushort4*>(xhf + o + 4) = hi;
  }
  s += __shfl_xor(s, 16);
  s += __shfl_xor(s, 32);
  if (quad == 0) sw[w * 16 + m] = s;
  __syncthreads();
  if (tid < 16) {
    int i = b * 16 + tid;
    float t = sw[tid] + sw[16 + tid] + sw[32 + tid] + sw[48 + tid];
    sqq[i] = fmaf(t, 128.f, 262144.f);   // pre-quantized for key calc
  }
  if (b == 0 && tid == 0) { *sum = 0.f; *cnt = 0; *done = 0; }
}

// ---- MFMA Gram + two-sided mining, 8 waves/block, no global atomics ----
__global__ __launch_bounds__(512) void k_mine16(
    const unsigned short* __restrict__ xhf, const int* __restrict__ lab,
    const float* __restrict__ sqq,
    unsigned* __restrict__ ppart, unsigned* __restrict__ npart) {
  __shared__ unsigned short Alds[8 * 8 * 512];   // 64 KB: [mtile 8][tk 8][512]
  __shared__ unsigned jbp[8 * 64], jbn[8 * 64];  // 4 KB: per-wave j-side partials

  // decode linear block id -> (bi, bj), bi <= bj, over 64x64 block grid
  int t  = blockIdx.x;
  int bi = (int)(64.5f - sqrtf(64.5f * 64.5f - 2.f * (float)t));
  int b0 = 64 * bi - (bi * (bi - 1)) / 2;
  if (t < b0) { bi--; b0 = 64 * bi - (bi * (bi - 1)) / 2; }
  else {
    int b1 = 64 * (bi + 1) - ((bi + 1) * bi) / 2;
    if (t >= b1) { bi++; b0 = b1; }
  }
  const int bj = bi + (t - b0);

  const int tid  = threadIdx.x;
  const int lane = tid & 63;
  const int w    = tid >> 6;          // 0..7
  const int wi   = w >> 1;            // 0..3 : 32-anchor band
  const int wj   = w & 1;             // 0..1 : 64-j half
  const int quad = lane >> 4, l15 = lane & 15;
  const int i0   = bi * 128;

  // stage A: contiguous 64 KB copy (already fragment-major), 512 threads
  {
    const short8* src = reinterpret_cast<const short8*>(xhf + (size_t)bi * 32768);
    short8* dst = reinterpret_cast<short8*>(Alds);
#pragma unroll
    for (int it = 0; it < 8; ++it) dst[it * 512 + tid] = src[it * 512 + tid];
  }

  // rows of this wave: r = mt*4+reg -> ir = i0 + wi*32 + mt*16 + quad*4 + reg
  unsigned pkey[8], nkey[8];
  unsigned lip = 0;
  float    sqi[8];
#pragma unroll
  for (int r = 0; r < 8; ++r) {
    pkey[r] = 0u; nkey[r] = 0xFFFFFFFFu;
    int ir = i0 + wi * 32 + (r >> 2) * 16 + quad * 4 + (r & 3);
    lip |= ((unsigned)lab[ir] & 0xFu) << (r * 4);
    sqi[r] = sqq[ir];
  }
  __syncthreads();

  const unsigned short* Bw = xhf + ((size_t)(bj * 8 + wj * 4) * 8) * 512 + lane * 8;
  const unsigned short* Aw = Alds + (size_t)(wi * 2) * 8 * 512 + lane * 8;

  floatx4 acc[8];
#pragma unroll
  for (int q = 0; q < 8; ++q) acc[q] = (floatx4)0.f;

#pragma unroll
  for (int tk = 0; tk < 8; ++tk) {
    short8 Bf[4];
#pragma unroll
    for (int nt = 0; nt < 4; ++nt)
      Bf[nt] = *reinterpret_cast<const short8*>(Bw + nt * 4096 + tk * 512);
    short8 Af[2];
#pragma unroll
    for (int mt = 0; mt < 2; ++mt)
      Af[mt] = *reinterpret_cast<const short8*>(Aw + (size_t)(mt * 8 + tk) * 512);
#pragma unroll
    for (int mt = 0; mt < 2; ++mt)
#pragma unroll
      for (int nt = 0; nt < 4; ++nt)
        acc[mt * 4 + nt] = __builtin_amdgcn_mfma_f32_16x16x32_bf16(
            Af[mt], Bf[nt], acc[mt * 4 + nt], 0, 0, 0);
  }

  // two-sided selection epilogue (keys as in R11/R15).
  // i-side: v_ij = sq_j - 2*dot -> key (cvt(sjq-256*dot)<<13)|j, umax/umin.
  // j-side: v_ji = sq_i - 2*dot -> key (cvt(sqi-256*dot)<<13)|i, same eq.
#pragma unroll
  for (int nt = 0; nt < 4; ++nt) {
    int      j  = bj * 128 + wj * 64 + nt * 16 + l15;
    unsigned jl = (unsigned)lab[j] & 0xFu;
    float    sj = sqq[j];
    unsigned jp = 0u, jn = 0xFFFFFFFFu;
#pragma unroll
    for (int r = 0; r < 8; ++r) {
      float dot = acc[(r >> 2) * 4 + nt][r & 3];
      int   ir  = i0 + wi * 32 + (r >> 2) * 16 + quad * 4 + (r & 3);
      bool  eq  = (jl == ((lip >> (r * 4)) & 0xFu));
      // i-side
      unsigned kqi  = (unsigned)fmaf(-256.f, dot, sj);
      unsigned keyi = (kqi << 13) | (unsigned)j;
      unsigned pci = eq ? keyi : 0u;
      unsigned nci = eq ? 0xFFFFFFFFu : keyi;
      pkey[r] = pkey[r] > pci ? pkey[r] : pci;
      nkey[r] = nkey[r] < nci ? nkey[r] : nci;
      // j-side
      unsigned kqj  = (unsigned)fmaf(-256.f, dot, sqi[r]);
      unsigned keyj = (kqj << 13) | (unsigned)ir;
      unsigned pcj = eq ? keyj : 0u;
      unsigned ncj = eq ? 0xFFFFFFFFu : keyj;
      jp = jp > pcj ? jp : pcj;
      jn = jn < ncj ? jn : ncj;
    }
    // reduce j-side across the 4 quads sharing this j, park in LDS
#pragma unroll
    for (int m = 16; m < 64; m <<= 1) {
      unsigned op = (unsigned)__shfl_xor((int)jp, m);
      unsigned on = (unsigned)__shfl_xor((int)jn, m);
      jp = jp > op ? jp : op;
      jn = jn < on ? jn : on;
    }
    if (quad == 0) {
      jbp[w * 64 + nt * 16 + l15] = jp;
      jbn[w * 64 + nt * 16 + l15] = jn;
    }
  }

  // i-side: reduce across the 16 l15-lanes, publish slot 2*bj+wj of band bi
#pragma unroll
  for (int r = 0; r < 8; ++r) {
    unsigned p = pkey[r], n = nkey[r];
#pragma unroll
    for (int m = 1; m < 16; m <<= 1) {
      unsigned op = (unsigned)__shfl_xor((int)p, m);
      unsigned on = (unsigned)__shfl_xor((int)n, m);
      p = p > op ? p : op;
      n = n < on ? n : on;
    }
    if (l15 == 0) {
      int ir = i0 + wi * 32 + (r >> 2) * 16 + quad * 4 + (r & 3);
      size_t idx = (size_t)(2 * bj + wj) * B_N + ir;
      ppart[idx] = p;
      npart[idx] = n;
    }
  }

  __syncthreads();
  // j-side combine across wi-pairs (w and w^2 share wj): waves wi in {0,2}
  // publish slot 2*bi + (wi>>1) of band bj. Diagonal skipped (i-side covers).
  if ((wi & 1) == 0 && bi != bj) {
    unsigned p = jbp[w * 64 + lane];
    unsigned n = jbn[w * 64 + lane];
    unsigned p2 = jbp[(w ^ 2) * 64 + lane];
    unsigned n2 = jbn[(w ^ 2) * 64 + lane];
    p = p > p2 ? p : p2;
    n = n < n2 ? n : n2;
    int j = bj * 128 + wj * 64 + lane;
    size_t idx = (size_t)(2 * bi + (wi >> 1)) * B_N + j;
    ppart[idx] = p;
    npart[idx] = n;
  }
}

// ---- slot-reduce + exact fp32 triplet distances + loss (R15's proven form) ----
__global__ void k_finish(const float* __restrict__ x,
                         const unsigned* __restrict__ ppart,
                         const unsigned* __restrict__ npart,
                         float* __restrict__ sum, int* __restrict__ cnt,
                         int* __restrict__ done, float* __restrict__ out) {
  __shared__ unsigned spk[32], snk[32];
  __shared__ float ssum[4];
  __shared__ int   scnt[4];
  const int tid = threadIdx.x;
  const int a0  = blockIdx.x * 32;

  if (tid < 32) { spk[tid] = 0u; snk[tid] = 0xFFFFFFFFu; }
  __syncthreads();

  {
    const int a    = a0 + (tid & 31);
    const int part = tid >> 5;           // 0..7 -> slots part*16 .. part*16+15
    unsigned p = 0u, n = 0xFFFFFFFFu;
#pragma unroll
    for (int s = 0; s < 16; ++s) {
      size_t idx = (size_t)(part * 16 + s) * B_N + a;
      unsigned pv = ppart[idx];
      unsigned nv = npart[idx];
      p = p > pv ? p : pv;
      n = n < nv ? n : nv;
    }
    atomicMax(&spk[tid & 31], p);        // LDS atomics: cheap, 8-way
    atomicMin(&snk[tid & 31], n);
  }
  __syncthreads();

  const int w = tid >> 6, lane = tid & 63;
  float lsum = 0.f; int lcnt = 0;
#pragma unroll
  for (int it = 0; it < 8; ++it) {
    int al = w * 8 + it;                 // 0..31
    int a  = a0 + al;
    unsigned p = spk[al];
    unsigned n = snk[al];
    bool valid = (p != 0u) && (n != 0xFFFFFFFFu);
    int  pidx = valid ? (int)(p & 8191u) : 0;
    int  nidx = valid ? (int)(n & 8191u) : 0;

    float4 xa = *reinterpret_cast<const float4*>(x + (size_t)a * D_K + lane * 4);
    float4 xp = *reinterpret_cast<const float4*>(x + (size_t)pidx * D_K + lane * 4);
    float4 xn = *reinterpret_cast<const float4*>(x + (size_t)nidx * D_K + lane * 4);
    float dx, sp = 0.f, sn = 0.f;
    dx = xa.x - xp.x + 1e-6f; sp = fmaf(dx, dx, sp);
    dx = xa.y - xp.y + 1e-6f; sp = fmaf(dx, dx, sp);
    dx = xa.z - xp.z + 1e-6f; sp = fmaf(dx, dx, sp);
    dx = xa.w - xp.w + 1e-6f; sp = fmaf(dx, dx, sp);
    dx = xa.x - xn.x + 1e-6f; sn = fmaf(dx, dx, sn);
    dx = xa.y - xn.y + 1e-6f; sn = fmaf(dx, dx, sn);
    dx = xa.z - xn.z + 1e-6f; sn = fmaf(dx, dx, sn);
    dx = xa.w - xn.w + 1e-6f; sn = fmaf(dx, dx, sn);
#pragma unroll
    for (int o = 32; o > 0; o >>= 1) {
      sp += __shfl_down(sp, o, 64);
      sn += __shfl_down(sn, o, 64);
    }
    if (lane == 0 && valid) {
      float per = sqrtf(sp) - sqrtf(sn) + 0.3f;
      if (per > 0.f) lsum += per;
      lcnt += 1;
    }
  }
  if (lane == 0) { ssum[w] = lsum; scnt[w] = lcnt; }
  __syncthreads();
  if (tid == 0) {
    atomicAdd(sum, ssum[0] + ssum[1] + ssum[2] + ssum[3]);
    atomicAdd(cnt, scnt[0] + scnt[1] + scnt[2] + scnt[3]);
    __threadfence();
    int prev = atomicAdd(done, 1);
    if (prev == gridDim.x - 1) {
      float s = atomicAdd(sum, 0.f);
      int   cc = atomicAdd(cnt, 0);
      if (cc < 1) cc = 1;
      out[0] = s / (float)cc;
    }
  }
}

extern "C" void kernel_launch(void* const* d_in, const int* in_sizes, int n_in,
                              void* d_out, int out_size, void* d_ws, size_t ws_size,
                              hipStream_t stream) {
  const float* x   = (const float*)d_in[0];
  const int*   lab = (const int*)d_in[1];
  float*       out = (float*)d_out;

  char* ws = (char*)d_ws;
  unsigned short* xhf = (unsigned short*)ws;                      // 4 MB
  float* sqq = (float*)(ws + (size_t)4608 * 1024);                // 32 KB
  char*  pb = ws + (size_t)4608 * 1024 + 65536;
  size_t seg = (size_t)128 * B_N * 4;                             // 4 MB each
  unsigned* ppart = (unsigned*)(pb);
  unsigned* npart = (unsigned*)(pb + seg);
  float* sum  = (float*)(pb + 2 * seg);
  int*   cnt  = (int*)(sum + 1);
  int*   done = (int*)(sum + 2);

  k_split<<<B_N / 16, 256, 0, stream>>>(x, xhf, sqq, sum, cnt, done);
  k_mine16<<<2080, 512, 0, stream>>>(xhf, lab, sqq, ppart, npart);
  k_finish<<<B_N / 32, 256, 0, stream>>>(x, ppart, npart, sum, cnt, done, out);
}